// Round 15
// baseline (34.632 us; speedup 1.0000x reference)
//
#include <hip/hip_runtime.h>
#include <hip/hip_bf16.h>

// Oja scan, reformulated. G[b][n][t] = row_n . x_t for n in [0,1088):
// rows 0..1023 = W0 rows, rows 1024..1087 = X rows (=> S = X X^T).
// Scan: exact projected Oja recurrence on u[j] = W_t . x_j:
//   y_t = sigmoid(u[t]);  u <- (1-lr*y^2)*u + (lr*y)*S[t,:]
// R15: isolate the cold W-read into a pure-streaming cvt kernel (R11's
// pattern: 2048 independent blocks, no barriers/LDS/MFMA) -> Wb16; the
// R14-style tiny-block gemm then stages bf16 A from L3-hot Wb16 (zero
// cold HBM in gemm). Scan = R14 (4-partial sum). This is simultaneously
// the fix (if streaming reads run at BW) and the decisive measurement
// (if not, the env's cold-read ceiling is the roofline).

#define BB 8
#define TT 64
#define NI 1024
#define NO 1024
#define NTOT 1088                      // 1024 W rows + 64 X rows
#define PSTR ((size_t)BB * NTOT * TT)  // floats per K-partial = 557056

typedef __attribute__((ext_vector_type(8))) short bf16x8;
typedef __attribute__((ext_vector_type(8))) short short8v;
typedef __attribute__((ext_vector_type(4))) float f32x4;

__device__ __forceinline__ short f2bf(float f) {
    __hip_bfloat16 h = __float2bfloat16(f);
    return __builtin_bit_cast(short, h);
}

// ---------- Kernel 0: W (8.39M) and X (0.52M) f32 -> bf16, pure stream ----------
// 2048 blocks x 256 thr; per thread: 2 chunks of 8 consecutive W floats
// (16 MB apart) + (first 65536 threads) 8 X floats. Max-MLP streaming.
__global__ __launch_bounds__(256)
void cvt_kernel(const float* __restrict__ W0, const float* __restrict__ X,
                ushort* __restrict__ Wb16, ushort* __restrict__ Xb16)
{
    const int t = blockIdx.x * 256 + threadIdx.x;   // 0..524287
#pragma unroll
    for (int q = 0; q < 2; ++q) {
        const size_t base = ((size_t)q * 524288 + t) * 8;
        const float4 v0 = *reinterpret_cast<const float4*>(W0 + base);
        const float4 v1 = *reinterpret_cast<const float4*>(W0 + base + 4);
        short8v s;
        s[0] = f2bf(v0.x); s[1] = f2bf(v0.y); s[2] = f2bf(v0.z); s[3] = f2bf(v0.w);
        s[4] = f2bf(v1.x); s[5] = f2bf(v1.y); s[6] = f2bf(v1.z); s[7] = f2bf(v1.w);
        *reinterpret_cast<short8v*>(Wb16 + base) = s;
    }
    if (t < 65536) {
        const size_t base = (size_t)t * 8;
        const float4 v0 = *reinterpret_cast<const float4*>(X + base);
        const float4 v1 = *reinterpret_cast<const float4*>(X + base + 4);
        short8v s;
        s[0] = f2bf(v0.x); s[1] = f2bf(v0.y); s[2] = f2bf(v0.z); s[3] = f2bf(v0.w);
        s[4] = f2bf(v1.x); s[5] = f2bf(v1.y); s[6] = f2bf(v1.z); s[7] = f2bf(v1.w);
        *reinterpret_cast<short8v*>(Xb16 + base) = s;
    }
}

// ---------- Kernel 1: Gpart[ks][b][n][t] partial GEMM (A from L3-hot Wb16) ----------
// Grid 2176: ks = bid&3, job = bid>>2 (b = job&7, nt = job>>3).
// Block 256 thr = 4 waves; wave w -> t-tile w*16; K-slice = ks*256..+256.
__global__ __launch_bounds__(256, 4)
void gemmp_kernel(const ushort* __restrict__ Wb16, const ushort* __restrict__ Xb16,
                  float* __restrict__ Gp)
{
    __shared__ __align__(16) ushort As[16 * 264];   // 8448 B (pad 8 shorts/row)

    const int tid  = threadIdx.x;
    const int lane = tid & 63;
    const int wave = tid >> 6;
    const int ks  = blockIdx.x & 3;
    const int job = blockIdx.x >> 2;     // 0..543
    const int b   = job & 7;
    const int nt  = job >> 3;            // 0..67
    const int n0  = nt * 16;
    const int t0  = wave * 16;

    const int r  = lane & 15;            // fragment row
    const int kb = lane >> 4;            // k-block 0..3 (8 k's each)

    // ---- B-frags -> registers (bf16, L2-hot; 8 x 16B) ----
    bf16x8 breg[8];
    {
        const ushort* __restrict__ Bbase =
            Xb16 + ((size_t)b * TT + t0 + r) * NI + ks * 256 + kb * 8;
#pragma unroll
        for (int kk = 0; kk < 8; ++kk)
            breg[kk] = *reinterpret_cast<const bf16x8*>(Bbase + kk * 32);
    }

    // ---- A stage: 16 rows x 256 bf16 from Wb16 (L3-hot), 32 B/thread ----
    const ushort* __restrict__ Abase =
        (((n0) < NO) ? (Wb16 + ((size_t)b * NO + n0) * NI)
                     : (Xb16 + ((size_t)b * TT + (n0 - NO)) * NI)) + ks * 256;
    {
        const int j = tid >> 4;          // row 0..15
        const int x = tid & 15;          // 16-bf16 slice within row
        const ushort* sr = Abase + (size_t)j * NI + x * 16;
        const bf16x8 s0 = *reinterpret_cast<const bf16x8*>(sr);
        const bf16x8 s1 = *reinterpret_cast<const bf16x8*>(sr + 8);
        *reinterpret_cast<bf16x8*>(&As[j * 264 + x * 16])     = s0;
        *reinterpret_cast<bf16x8*>(&As[j * 264 + x * 16 + 8]) = s1;
    }
    __syncthreads();

    // ---- 8 x (ds_read_b128 + MFMA) ----
    f32x4 acc = {0.f, 0.f, 0.f, 0.f};
    const ushort* __restrict__ Ap = &As[r * 264 + kb * 8];
#pragma unroll
    for (int kk = 0; kk < 8; ++kk) {
        const bf16x8 a = *reinterpret_cast<const bf16x8*>(Ap + kk * 32);
        acc = __builtin_amdgcn_mfma_f32_16x16x32_bf16(a, breg[kk], acc, 0, 0, 0);
    }

    // D layout: col t = lane&15, row n = (lane>>4)*4 + rr   [m89-verified]
    const int tcol = lane & 15;
    const int mrow = (lane >> 4) * 4;
    float* __restrict__ Gout = Gp + (size_t)ks * PSTR;
#pragma unroll
    for (int rr = 0; rr < 4; ++rr)
        Gout[((size_t)b * NTOT + n0 + mrow + rr) * TT + t0 + tcol] = acc[rr];
}

// ---------- Kernel 2: lane-parallel projected-Oja scan ----------
// 512 blocks x 256 thr (4 waves). Block: batch b = bid&7, 16 o-rows.
// Reads 4 K-partials and sums (fp32).
__global__ __launch_bounds__(256, 8)
void scan_kernel(const float* __restrict__ Gp, float* __restrict__ out)
{
    __shared__ float Sl[TT][TT];
    __shared__ float ybuf[16][68];

    const int tid  = threadIdx.x;
    const int lane = tid & 63;
    const int wave = tid >> 6;
    const int b  = blockIdx.x & 7;
    const int o0 = (blockIdx.x >> 3) * 16;

    // stage S[b]: sum of 4 partials of rows 1024..1087
    {
        const size_t off = ((size_t)b * NTOT + NO) * TT;
        const float4* p0 = reinterpret_cast<const float4*>(Gp + 0 * PSTR + off);
        const float4* p1 = reinterpret_cast<const float4*>(Gp + 1 * PSTR + off);
        const float4* p2 = reinterpret_cast<const float4*>(Gp + 2 * PSTR + off);
        const float4* p3 = reinterpret_cast<const float4*>(Gp + 3 * PSTR + off);
        float4* dst = reinterpret_cast<float4*>(&Sl[0][0]);
#pragma unroll
        for (int q = 0; q < 4; ++q) {
            const int idx = tid + q * 256;
            const float4 a = p0[idx], c = p1[idx], d = p2[idx], e = p3[idx];
            float4 s;
            s.x = a.x + c.x + d.x + e.x;
            s.y = a.y + c.y + d.y + e.y;
            s.z = a.z + c.z + d.z + e.z;
            s.w = a.w + c.w + d.w + e.w;
            dst[idx] = s;
        }
    }

    const int r  = lane & 3;
    const int jb = lane >> 2;
    const int row = o0 + wave * 4 + r;

    // u init: sum of 4 partials
    float u0, u1, u2, u3;
    {
        const size_t go = ((size_t)b * NTOT + row) * TT + jb * 4;
        const float4 a = *reinterpret_cast<const float4*>(Gp + 0 * PSTR + go);
        const float4 c = *reinterpret_cast<const float4*>(Gp + 1 * PSTR + go);
        const float4 d = *reinterpret_cast<const float4*>(Gp + 2 * PSTR + go);
        const float4 e = *reinterpret_cast<const float4*>(Gp + 3 * PSTR + go);
        u0 = a.x + c.x + d.x + e.x;
        u1 = a.y + c.y + d.y + e.y;
        u2 = a.z + c.z + d.z + e.z;
        u3 = a.w + c.w + d.w + e.w;
    }

    __syncthreads();

    const float lr   = 1.0f / 1024.0f;
    const float nL2E = -1.44269504f;
    float y0 = 0.f, y1 = 0.f, y2 = 0.f, y3 = 0.f;

#pragma unroll
    for (int t = 0; t < TT; ++t) {
        const int srcl = (t & 0x3C) | r;
        const float uv = ((t & 3) == 0) ? u0 : ((t & 3) == 1) ? u1
                       : ((t & 3) == 2) ? u2 : u3;
        const float pre = __shfl(uv, srcl, 64);

        const float e = __builtin_amdgcn_exp2f(pre * nL2E);
        const float y = __builtin_amdgcn_rcpf(1.0f + e);

        const bool own = (jb == (t >> 2));
        if ((t & 3) == 0) y0 = own ? y : y0;
        if ((t & 3) == 1) y1 = own ? y : y1;
        if ((t & 3) == 2) y2 = own ? y : y2;
        if ((t & 3) == 3) y3 = own ? y : y3;

        const float c2 = lr * y;
        const float c1 = fmaf(-c2, y, 1.0f);

        const float4 s = *reinterpret_cast<const float4*>(&Sl[t][jb * 4]);
        u0 = fmaf(c1, u0, c2 * s.x);
        u1 = fmaf(c1, u1, c2 * s.y);
        u2 = fmaf(c1, u2, c2 * s.z);
        u3 = fmaf(c1, u3, c2 * s.w);
    }

    {
        float4 yv; yv.x = y0; yv.y = y1; yv.z = y2; yv.w = y3;
        *reinterpret_cast<float4*>(&ybuf[wave * 4 + r][jb * 4]) = yv;
    }
    __syncthreads();

    {
        const int t = tid >> 2;
        const int g = tid & 3;
        float4 ov;
        ov.x = ybuf[g * 4 + 0][t];
        ov.y = ybuf[g * 4 + 1][t];
        ov.z = ybuf[g * 4 + 2][t];
        ov.w = ybuf[g * 4 + 3][t];
        *reinterpret_cast<float4*>(
            &out[(size_t)b * TT * NO + (size_t)t * NO + o0 + g * 4]) = ov;
    }
}

extern "C" void kernel_launch(void* const* d_in, const int* in_sizes, int n_in,
                              void* d_out, int out_size, void* d_ws, size_t ws_size,
                              hipStream_t stream) {
    const float* X  = (const float*)d_in[0];   // [8][64][1024]
    const float* W0 = (const float*)d_in[1];   // [8][1024][1024]
    float* out = (float*)d_out;                // [8][64][1024]

    float*  Gp   = (float*)d_ws;                          // 4 x 557056 f32 = 8,912,896 B
    ushort* Xb16 = (ushort*)((char*)d_ws + 8912896);      // 1,048,576 B
    ushort* Wb16 = (ushort*)((char*)d_ws + 9961472);      // 16,777,216 B

    cvt_kernel<<<2048, 256, 0, stream>>>(W0, X, Wb16, Xb16);
    gemmp_kernel<<<4 * 544, 256, 0, stream>>>(Wb16, Xb16, Gp);
    scan_kernel<<<512, 256, 0, stream>>>(Gp, out);
}

// Round 16
// 31.296 us; speedup vs baseline: 1.1066x; 1.1066x over previous
//
#include <hip/hip_runtime.h>
#include <hip/hip_bf16.h>

// Oja scan, reformulated. G[b][n][t] = row_n . x_t for n in [0,1088):
// rows 0..1023 = W0 rows, rows 1024..1087 = X rows (=> S = X X^T).
// Scan: exact projected Oja recurrence on u[j] = W_t . x_j:
//   y_t = sigmoid(u[t]);  u <- (1-lr*y^2)*u + (lr*y)*S[t,:]
// R16: exactly R13 (best, 30.2us) with ONE variable changed: the A-panel
// f32 loads use __builtin_nontemporal_load (bypass L3 allocation). Theory:
// harness poison-fills leave L3 fully dirty; cold reads stall on dirty-line
// writeback slots (~1.6 TB/s). NT loads skip allocation -> raw HBM rate.

#define BB 8
#define TT 64
#define NI 1024
#define NO 1024
#define NTOT 1088            // 1024 W rows + 64 X rows
#define NTILES 68            // NTOT/16

typedef __attribute__((ext_vector_type(8))) short bf16x8;
typedef __attribute__((ext_vector_type(4))) float f32x4;
typedef __attribute__((ext_vector_type(4))) float f32x4v;

__device__ __forceinline__ short f2bf(float f) {
    __hip_bfloat16 h = __float2bfloat16(f);
    return __builtin_bit_cast(short, h);
}

// ---------- Kernel 0: X (f32, 0.52M elems) -> bf16 ----------
__global__ __launch_bounds__(256)
void xcvt_kernel(const float* __restrict__ X, ushort* __restrict__ Xb16)
{
    const int i = blockIdx.x * 256 + threadIdx.x;   // float4 index, 131072 total
    const float4 v = *reinterpret_cast<const float4*>(X + (size_t)i * 4);
    short4 s;
    s.x = f2bf(v.x); s.y = f2bf(v.y); s.z = f2bf(v.z); s.w = f2bf(v.w);
    *reinterpret_cast<short4*>(Xb16 + (size_t)i * 4) = s;
}

// ---------- Kernel 1: G[b][n][t] via MFMA ----------
// Grid 272 = 34 slots x 8 batches (b = blockIdx&7). Block: 256 thr, 4 waves;
// wave w owns t-tile w for BOTH panels nt = slot*2, slot*2+1.
__global__ __launch_bounds__(256, 1)
void gemm_kernel(const float* __restrict__ X, const float* __restrict__ W0,
                 const ushort* __restrict__ Xb16, float* __restrict__ G)
{
    __shared__ __align__(16) ushort As[2][16 * 1024];   // 2 x 32 KB bf16

    const int tid  = threadIdx.x;
    const int lane = tid & 63;
    const int wave = tid >> 6;
    const int b    = blockIdx.x & 7;
    const int slot = blockIdx.x >> 3;    // 0..33
    const int nt0  = slot * 2;
    const int t0   = wave * 16;

    const int r  = lane & 15;            // fragment row
    const int kb = lane >> 4;            // k-block 0..3

    // ---- B-tile -> registers (once; inner loop has no global loads) ----
    bf16x8 breg[32];
    {
        const ushort* __restrict__ Bbase =
            Xb16 + ((size_t)b * TT + t0 + r) * NI + kb * 8;
#pragma unroll
        for (int kk = 0; kk < 32; ++kk)
            breg[kk] = *reinterpret_cast<const bf16x8*>(Bbase + kk * 32);
    }

    // ---- stage mapping: thread (j = tid>>4 row, x = tid&15), 16 chunks ----
    const int j  = tid >> 4;
    const int x  = tid & 15;
    const int sj = (j & 7) << 4;         // XOR swizzle for row j

    const float* __restrict__ Xb = X + (size_t)b * TT * NI;
    const float* __restrict__ Wb = W0 + (size_t)b * NO * NI;
#define SRCROW(nt) ((((nt) * 16) < NO) ? (Wb + ((size_t)((nt) * 16) + j) * NI) \
                                       : (Xb + ((size_t)((nt) * 16 - NO) + j) * NI))

    f32x4v v[16];
    // prologue: load panel 0 (16 x float4/thread, one burst, NON-TEMPORAL)
    {
        const float* sr = SRCROW(nt0) + x * 4;
#pragma unroll
        for (int c = 0; c < 16; ++c)
            v[c] = __builtin_nontemporal_load(
                reinterpret_cast<const f32x4v*>(sr + c * 64));
    }
    // cvt + swizzled ds_write -> buf 0
#pragma unroll
    for (int c = 0; c < 16; ++c) {
        short4 s4;
        s4.x = f2bf(v[c][0]); s4.y = f2bf(v[c][1]);
        s4.z = f2bf(v[c][2]); s4.w = f2bf(v[c][3]);
        char* dst = (char*)As[0] + j * 2048 + c * 128 + ((x * 8) ^ sj);
        *reinterpret_cast<short4*>(dst) = s4;
    }
    __syncthreads();

    // swizzled read bases (verified: phys = r*2048 + ((kb^(r&3))<<4)
    //  | (((kk&1)^((r>>2)&1))<<6) + (kk>>1)*128 )
    const int lanebyte = (r << 11) | ((kb ^ (r & 3)) << 4);
    const int rbit = (r >> 2) & 1;

    const int tcol = lane & 15;
    const int mrow = (lane >> 4) * 4;

#pragma unroll
    for (int p = 0; p < 2; ++p) {
        if (p == 0) {
            // issue panel-1 loads now; they fly during panel-0 compute
            const float* sr = SRCROW(nt0 + 1) + x * 4;
#pragma unroll
            for (int c = 0; c < 16; ++c)
                v[c] = __builtin_nontemporal_load(
                    reinterpret_cast<const f32x4v*>(sr + c * 64));
        }

        const char* base = (const char*)As[p] + lanebyte;
        const char* ApE = base + (rbit << 6);
        const char* ApO = base + ((rbit ^ 1) << 6);

        f32x4 acc = {0.f, 0.f, 0.f, 0.f};
#pragma unroll
        for (int kk2 = 0; kk2 < 16; ++kk2) {
            const bf16x8 ae = *reinterpret_cast<const bf16x8*>(ApE + kk2 * 128);
            acc = __builtin_amdgcn_mfma_f32_16x16x32_bf16(ae, breg[2 * kk2], acc, 0, 0, 0);
            const bf16x8 ao = *reinterpret_cast<const bf16x8*>(ApO + kk2 * 128);
            acc = __builtin_amdgcn_mfma_f32_16x16x32_bf16(ao, breg[2 * kk2 + 1], acc, 0, 0, 0);
        }

        // D layout: col t = lane&15, row n = (lane>>4)*4 + rr  [m89-verified]
        const int n0 = (nt0 + p) * 16;
#pragma unroll
        for (int rr = 0; rr < 4; ++rr)
            G[((size_t)b * NTOT + n0 + mrow + rr) * TT + t0 + tcol] = acc[rr];

        if (p == 0) {
            // write-late: cvt + ds_write panel 1 into buf 1, then barrier
#pragma unroll
            for (int c = 0; c < 16; ++c) {
                short4 s4;
                s4.x = f2bf(v[c][0]); s4.y = f2bf(v[c][1]);
                s4.z = f2bf(v[c][2]); s4.w = f2bf(v[c][3]);
                char* dst = (char*)As[1] + j * 2048 + c * 128 + ((x * 8) ^ sj);
                *reinterpret_cast<short4*>(dst) = s4;
            }
            __syncthreads();
        }
    }
#undef SRCROW
}

// ---------- Kernel 2: lane-parallel projected-Oja scan (R10) ----------
__global__ __launch_bounds__(256, 8)
void scan_kernel(const float* __restrict__ G, float* __restrict__ out)
{
    __shared__ float Sl[TT][TT];
    __shared__ float ybuf[16][68];

    const int tid  = threadIdx.x;
    const int lane = tid & 63;
    const int wave = tid >> 6;
    const int b  = blockIdx.x & 7;
    const int o0 = (blockIdx.x >> 3) * 16;

    {
        const float4* __restrict__ src =
            reinterpret_cast<const float4*>(G + ((size_t)b * NTOT + NO) * TT);
        float4* dst = reinterpret_cast<float4*>(&Sl[0][0]);
#pragma unroll
        for (int q = 0; q < 4; ++q)
            dst[tid + q * 256] = src[tid + q * 256];
    }

    const int r  = lane & 3;
    const int jb = lane >> 2;
    const int row = o0 + wave * 4 + r;

    const float4 uu = *reinterpret_cast<const float4*>(
        G + ((size_t)b * NTOT + row) * TT + jb * 4);
    float u0 = uu.x, u1 = uu.y, u2 = uu.z, u3 = uu.w;

    __syncthreads();

    const float lr   = 1.0f / 1024.0f;
    const float nL2E = -1.44269504f;
    float y0 = 0.f, y1 = 0.f, y2 = 0.f, y3 = 0.f;

#pragma unroll
    for (int t = 0; t < TT; ++t) {
        const int srcl = (t & 0x3C) | r;
        const float uv = ((t & 3) == 0) ? u0 : ((t & 3) == 1) ? u1
                       : ((t & 3) == 2) ? u2 : u3;
        const float pre = __shfl(uv, srcl, 64);

        const float e = __builtin_amdgcn_exp2f(pre * nL2E);
        const float y = __builtin_amdgcn_rcpf(1.0f + e);

        const bool own = (jb == (t >> 2));
        if ((t & 3) == 0) y0 = own ? y : y0;
        if ((t & 3) == 1) y1 = own ? y : y1;
        if ((t & 3) == 2) y2 = own ? y : y2;
        if ((t & 3) == 3) y3 = own ? y : y3;

        const float c2 = lr * y;
        const float c1 = fmaf(-c2, y, 1.0f);

        const float4 s = *reinterpret_cast<const float4*>(&Sl[t][jb * 4]);
        u0 = fmaf(c1, u0, c2 * s.x);
        u1 = fmaf(c1, u1, c2 * s.y);
        u2 = fmaf(c1, u2, c2 * s.z);
        u3 = fmaf(c1, u3, c2 * s.w);
    }

    {
        float4 yv; yv.x = y0; yv.y = y1; yv.z = y2; yv.w = y3;
        *reinterpret_cast<float4*>(&ybuf[wave * 4 + r][jb * 4]) = yv;
    }
    __syncthreads();

    {
        const int t = tid >> 2;
        const int g = tid & 3;
        float4 ov;
        ov.x = ybuf[g * 4 + 0][t];
        ov.y = ybuf[g * 4 + 1][t];
        ov.z = ybuf[g * 4 + 2][t];
        ov.w = ybuf[g * 4 + 3][t];
        *reinterpret_cast<float4*>(
            &out[(size_t)b * TT * NO + (size_t)t * NO + o0 + g * 4]) = ov;
    }
}

extern "C" void kernel_launch(void* const* d_in, const int* in_sizes, int n_in,
                              void* d_out, int out_size, void* d_ws, size_t ws_size,
                              hipStream_t stream) {
    const float* X  = (const float*)d_in[0];   // [8][64][1024]
    const float* W0 = (const float*)d_in[1];   // [8][1024][1024]
    float* out = (float*)d_out;                // [8][64][1024]

    float*  G    = (float*)d_ws;                          // 2,228,224 B
    ushort* Xb16 = (ushort*)((char*)d_ws + 2228224);      // 1,048,576 B

    xcvt_kernel<<<512, 256, 0, stream>>>(X, Xb16);
    gemm_kernel<<<34 * BB, 256, 0, stream>>>(X, W0, Xb16, G);
    scan_kernel<<<512, 256, 0, stream>>>(G, out);
}